// Round 12
// baseline (96.342 us; speedup 1.0000x reference)
//
#include <hip/hip_runtime.h>
#include <math.h>

__device__ __forceinline__ float silu_act(float y) {
    return y / (1.f + __expf(-y));
}

// Pointwise 1x1 conv + scale/bias + SiLU. Compile-time Cin for full unroll.
template<int TC, int CIN>
__global__ void pw_conv_silu(const float* __restrict__ in, int HW, int B,
                             const float* __restrict__ w,
                             const float* __restrict__ sc, const float* __restrict__ bi,
                             float* __restrict__ out, int CoutStride) {
    int g = blockIdx.x * blockDim.x + threadIdx.x;
    if (g >= B * HW) return;
    int b = g / HW, pix = g - b * HW;
    int co0 = blockIdx.y * TC;
    float acc[TC];
#pragma unroll
    for (int j = 0; j < TC; ++j) acc[j] = 0.f;
    const float* ip = in + (size_t)b * CIN * HW + pix;
    const float* wp = w + (size_t)co0 * CIN;
#pragma unroll 8
    for (int ci = 0; ci < CIN; ++ci) {
        float v = ip[(size_t)ci * HW];
#pragma unroll
        for (int j = 0; j < TC; ++j)
            acc[j] = fmaf(v, wp[j * CIN + ci], acc[j]);
    }
#pragma unroll
    for (int j = 0; j < TC; ++j) {
        int co = co0 + j;
        float y = fmaf(acc[j], sc[co], bi[co]);
        out[((size_t)b * CoutStride + co) * HW + pix] = silu_act(y);
    }
}

// fusedA (round-9-proven, ~7 us): comp dw3/dw5 + comp px (1x1).
__global__ __launch_bounds__(256) void fusedA_kernel(
        const float* __restrict__ x1c,
        const float* __restrict__ w3, const float* __restrict__ s3, const float* __restrict__ b3,
        const float* __restrict__ w5, const float* __restrict__ s5, const float* __restrict__ b5,
        const float* __restrict__ pxw, const float* __restrict__ pxs, const float* __restrict__ pxb,
        float* __restrict__ y) {
    const int H = 64, Wd = 64, HW = 4096;
    int Y = blockIdx.x, og = blockIdx.y, b = blockIdx.z;
    __shared__ float cat[64][64];
    int t = threadIdx.x;
    int l = t & 63;
    int w = __builtin_amdgcn_readfirstlane(t >> 6);
    const float* src = x1c + (size_t)b * 32 * HW;
#pragma unroll
    for (int k = 0; k < 8; ++k) {
        int c = w + 4 * k;
        const float* ip = src + (size_t)c * HW;
        float acc = 0.f, sc, bi;
        if (c < 16) {
            const float* wk = w3 + c * 9;
#pragma unroll
            for (int p = 0; p < 3; ++p) {
                int iy = Y + p - 1;
                if ((unsigned)iy >= (unsigned)H) continue;
#pragma unroll
                for (int kx = 0; kx < 3; ++kx) {
                    int ix = l + kx - 1;
                    if ((unsigned)ix >= (unsigned)Wd) continue;
                    acc = fmaf(ip[iy * Wd + ix], wk[p * 3 + kx], acc);
                }
            }
            sc = s3[c]; bi = b3[c];
        } else {
            const float* wk = w5 + (c - 16) * 25;
#pragma unroll
            for (int p = 0; p < 5; ++p) {
                int iy = Y + p - 2;
                if ((unsigned)iy >= (unsigned)H) continue;
#pragma unroll
                for (int kx = 0; kx < 5; ++kx) {
                    int ix = l + kx - 2;
                    if ((unsigned)ix >= (unsigned)Wd) continue;
                    acc = fmaf(ip[iy * Wd + ix], wk[p * 5 + kx], acc);
                }
            }
            sc = s5[c - 16]; bi = b5[c - 16];
        }
        cat[c][l] = ip[Y * Wd + l];
        cat[32 + c][l] = silu_act(fmaf(acc, sc, bi));
    }
    __syncthreads();
    {
        int co0 = og * 16 + w * 4;
        const float* wp = pxw + (size_t)co0 * 64;
        float acc[4] = {0.f, 0.f, 0.f, 0.f};
#pragma unroll 8
        for (int ci = 0; ci < 64; ++ci) {
            float xv = cat[ci][l];
#pragma unroll
            for (int k = 0; k < 4; ++k)
                acc[k] = fmaf(xv, wp[k * 64 + ci], acc[k]);
        }
#pragma unroll
        for (int k = 0; k < 4; ++k) {
            int co = co0 + k;
            y[((size_t)b * 64 + co) * HW + Y * Wd + l] =
                silu_act(fmaf(acc[k], pxs[co], pxb[co]));
        }
    }
}

// fusedB-lite: enc dw3/dw5 + enc px (1x1), exact fusedA shape.
// Block = (Y, og in 0..4, b) = 640 blocks, 320 threads (5 waves).
// Wave w: dw channels c = w + 5k (k<10, unguarded); px outputs
// co = og*20 + w*4 + {0..3} with wave-uniform (SGPR) weights. Raw wraw out.
__global__ __launch_bounds__(320) void fusedB_kernel(
        const float* __restrict__ x1e,
        const float* __restrict__ w3, const float* __restrict__ s3, const float* __restrict__ b3,
        const float* __restrict__ w5, const float* __restrict__ s5, const float* __restrict__ b5,
        const float* __restrict__ pxw, const float* __restrict__ pxs, const float* __restrict__ pxb,
        float* __restrict__ wraw) {
    const int H = 64, Wd = 64, HW = 4096;
    int Y = blockIdx.x, og = blockIdx.y, b = blockIdx.z;
    __shared__ float cat[100][64];    // x1e (0..49), dw (50..99)
    int t = threadIdx.x;
    int l = t & 63;
    int w = __builtin_amdgcn_readfirstlane(t >> 6);   // 0..4
    const float* src = x1e + (size_t)b * 50 * HW;
#pragma unroll
    for (int k = 0; k < 10; ++k) {
        int c = w + 5 * k;            // covers 0..49 exactly
        const float* ip = src + (size_t)c * HW;
        float acc = 0.f, sc, bi;
        if (c < 25) {
            const float* wk = w3 + c * 9;
#pragma unroll
            for (int p = 0; p < 3; ++p) {
                int iy = Y + p - 1;
                if ((unsigned)iy >= (unsigned)H) continue;
#pragma unroll
                for (int kx = 0; kx < 3; ++kx) {
                    int ix = l + kx - 1;
                    if ((unsigned)ix >= (unsigned)Wd) continue;
                    acc = fmaf(ip[iy * Wd + ix], wk[p * 3 + kx], acc);
                }
            }
            sc = s3[c]; bi = b3[c];
        } else {
            const float* wk = w5 + (c - 25) * 25;
#pragma unroll
            for (int p = 0; p < 5; ++p) {
                int iy = Y + p - 2;
                if ((unsigned)iy >= (unsigned)H) continue;
#pragma unroll
                for (int kx = 0; kx < 5; ++kx) {
                    int ix = l + kx - 2;
                    if ((unsigned)ix >= (unsigned)Wd) continue;
                    acc = fmaf(ip[iy * Wd + ix], wk[p * 5 + kx], acc);
                }
            }
            sc = s5[c - 25]; bi = b5[c - 25];
        }
        cat[c][l] = ip[Y * Wd + l];
        cat[50 + c][l] = silu_act(fmaf(acc, sc, bi));
    }
    __syncthreads();
    // enc px: wave w computes co = og*20 + w*4 + {0..3}
    {
        int co0 = og * 20 + w * 4;
        const float* wp = pxw + (size_t)co0 * 100;
        float acc[4] = {0.f, 0.f, 0.f, 0.f};
#pragma unroll 10
        for (int ci = 0; ci < 100; ++ci) {
            float xv = cat[ci][l];
#pragma unroll
            for (int k = 0; k < 4; ++k)
                acc[k] = fmaf(xv, wp[k * 100 + ci], acc[k]);
        }
#pragma unroll
        for (int k = 0; k < 4; ++k) {
            int co = co0 + k;
            wraw[((size_t)b * 100 + co) * HW + Y * Wd + l] =
                silu_act(fmaf(acc[k], pxs[co], pxb[co]));
        }
    }
}

// CARAFE v7: 2x LDS reuse. Thread = (l = t&63, w = t>>6): r = w&1 (oy
// offset), cg = w>>1 (channel subgroup). Holds wreg[2][25] (both ox
// parities, softmaxed in-register), computes 4 channels x 2 outputs.
// Block = (Y, 8-ch chunk, b) = 2048 blocks, LDS 10.9 KB.
__global__ __launch_bounds__(256) void carafe_kernel(
        const float* __restrict__ X, const float* __restrict__ wraw,
        float* __restrict__ out) {
    const int H = 64, Wd = 64, C = 128, Ho = 128, Wo = 128, HW = H * Wd;
    int Y = blockIdx.x;           // 0..63
    int cchunk = blockIdx.y;      // 0..15
    int b = blockIdx.z;
    __shared__ float xs[8][5][68];
    int t = threadIdx.x;
    int c0 = cchunk * 8;
    const float* Xb = X + ((size_t)b * C + c0) * HW;
    for (int i = t; i < 8 * 5 * 68; i += 256) {
        int col = i % 68;
        int tmp = i / 68;
        int p = tmp % 5;
        int c = tmp / 5;
        int iy = Y + p - 2, ix = col - 2;
        float v = 0.f;
        if ((unsigned)iy < (unsigned)H && (unsigned)ix < (unsigned)Wd)
            v = Xb[(size_t)c * HW + iy * Wd + ix];
        xs[c][p][col] = v;
    }
    int l = t & 63;
    int w = t >> 6;
    int r = w & 1;                // oy = 2Y + r
    int cg = w >> 1;              // channels cg*4 .. cg*4+3
    // load + softmax this thread's two weight sets: rp = 2r (ox=2l), 2r+1
    const float* wb = wraw + (size_t)b * 100 * HW + Y * Wd + l;
    float wreg[2][25];
#pragma unroll
    for (int par = 0; par < 2; ++par) {
        int rp = 2 * r + par;
#pragma unroll
        for (int j = 0; j < 25; ++j)
            wreg[par][j] = wb[(size_t)(j * 4 + rp) * HW];
        float m = -1e30f;
#pragma unroll
        for (int j = 0; j < 25; ++j) m = fmaxf(m, wreg[par][j]);
        float s = 0.f;
#pragma unroll
        for (int j = 0; j < 25; ++j) { wreg[par][j] = __expf(wreg[par][j] - m); s += wreg[par][j]; }
        float inv = 1.f / s;
#pragma unroll
        for (int j = 0; j < 25; ++j) wreg[par][j] *= inv;
    }
    __syncthreads();

    int oy = 2 * Y + r;
#pragma unroll
    for (int k = 0; k < 4; ++k) {
        int kc = cg * 4 + k;
        float a0 = 0.f, a1 = 0.f;
#pragma unroll
        for (int p = 0; p < 5; ++p)
#pragma unroll
            for (int q = 0; q < 5; ++q) {
                float v = xs[kc][p][l + q];
                int j = p * 5 + q;
                a0 = fmaf(wreg[0][j], v, a0);
                a1 = fmaf(wreg[1][j], v, a1);
            }
        size_t ob = (((size_t)b * C + (c0 + kc)) * Ho + oy) * Wo + 2 * l;
        *reinterpret_cast<float2*>(&out[ob]) = make_float2(a0, a1);
    }
}

extern "C" void kernel_launch(void* const* d_in, const int* in_sizes, int n_in,
                              void* d_out, int out_size, void* d_ws, size_t ws_size,
                              hipStream_t stream) {
    const float* X          = (const float*)d_in[0];
    const float* comp_cv1_w = (const float*)d_in[1];
    const float* comp_cv1_s = (const float*)d_in[2];
    const float* comp_cv1_b = (const float*)d_in[3];
    const float* comp_dw3_w = (const float*)d_in[4];
    const float* comp_dw3_s = (const float*)d_in[5];
    const float* comp_dw3_b = (const float*)d_in[6];
    const float* comp_dw5_w = (const float*)d_in[7];
    const float* comp_dw5_s = (const float*)d_in[8];
    const float* comp_dw5_b = (const float*)d_in[9];
    const float* comp_px_w  = (const float*)d_in[10];
    const float* comp_px_s  = (const float*)d_in[11];
    const float* comp_px_b  = (const float*)d_in[12];
    const float* enc_cv1_w  = (const float*)d_in[13];
    const float* enc_cv1_s  = (const float*)d_in[14];
    const float* enc_cv1_b  = (const float*)d_in[15];
    const float* enc_dw3_w  = (const float*)d_in[16];
    const float* enc_dw3_s  = (const float*)d_in[17];
    const float* enc_dw3_b  = (const float*)d_in[18];
    const float* enc_dw5_w  = (const float*)d_in[19];
    const float* enc_dw5_s  = (const float*)d_in[20];
    const float* enc_dw5_b  = (const float*)d_in[21];
    const float* enc_px_w   = (const float*)d_in[22];
    const float* enc_px_s   = (const float*)d_in[23];
    const float* enc_px_b   = (const float*)d_in[24];
    float* out = (float*)d_out;

    const int B = 2, HW = 64 * 64;
    float* x1c  = (float*)d_ws;                  // [B, 32, HW]
    float* yc   = x1c  + (size_t)B * 32 * HW;    // [B, 64, HW]
    float* x1e  = yc   + (size_t)B * 64 * HW;    // [B, 50, HW]
    float* wraw = x1e  + (size_t)B * 50 * HW;    // [B, 100, HW]

    int pixBlocks = (B * HW + 255) / 256;   // 32

    // 1. comp cv1 (1x1, 128 -> 32)
    pw_conv_silu<4, 128><<<dim3(pixBlocks, 8), 256, 0, stream>>>(
        X, HW, B, comp_cv1_w, comp_cv1_s, comp_cv1_b, x1c, 32);

    // 2. comp dw + comp px (fusedA, 512 blocks)
    fusedA_kernel<<<dim3(64, 4, B), 256, 0, stream>>>(
        x1c,
        comp_dw3_w, comp_dw3_s, comp_dw3_b,
        comp_dw5_w, comp_dw5_s, comp_dw5_b,
        comp_px_w, comp_px_s, comp_px_b,
        yc);

    // 3. enc cv1 (1x1, 64 -> 50)
    pw_conv_silu<5, 64><<<dim3(pixBlocks, 10), 256, 0, stream>>>(
        yc, HW, B, enc_cv1_w, enc_cv1_s, enc_cv1_b, x1e, 50);

    // 4. enc dw + enc px (fusedB-lite, 640 blocks x 320 thr)
    fusedB_kernel<<<dim3(64, 5, B), 320, 0, stream>>>(
        x1e,
        enc_dw3_w, enc_dw3_s, enc_dw3_b,
        enc_dw5_w, enc_dw5_s, enc_dw5_b,
        enc_px_w, enc_px_s, enc_px_b,
        wraw);

    // 5. CARAFE v7 (2x reuse, softmax in-register), 2048 blocks
    carafe_kernel<<<dim3(64, 16, B), 256, 0, stream>>>(X, wraw, out);
}

// Round 13
// 92.081 us; speedup vs baseline: 1.0463x; 1.0463x over previous
//
#include <hip/hip_runtime.h>
#include <math.h>

__device__ __forceinline__ float silu_act(float y) {
    return y / (1.f + __expf(-y));
}

// Pointwise 1x1 conv + scale/bias + SiLU. Compile-time Cin for full unroll.
template<int TC, int CIN>
__global__ void pw_conv_silu(const float* __restrict__ in, int HW, int B,
                             const float* __restrict__ w,
                             const float* __restrict__ sc, const float* __restrict__ bi,
                             float* __restrict__ out, int CoutStride) {
    int g = blockIdx.x * blockDim.x + threadIdx.x;
    if (g >= B * HW) return;
    int b = g / HW, pix = g - b * HW;
    int co0 = blockIdx.y * TC;
    float acc[TC];
#pragma unroll
    for (int j = 0; j < TC; ++j) acc[j] = 0.f;
    const float* ip = in + (size_t)b * CIN * HW + pix;
    const float* wp = w + (size_t)co0 * CIN;
#pragma unroll 8
    for (int ci = 0; ci < CIN; ++ci) {
        float v = ip[(size_t)ci * HW];
#pragma unroll
        for (int j = 0; j < TC; ++j)
            acc[j] = fmaf(v, wp[j * CIN + ci], acc[j]);
    }
#pragma unroll
    for (int j = 0; j < TC; ++j) {
        int co = co0 + j;
        float y = fmaf(acc[j], sc[co], bi[co]);
        out[((size_t)b * CoutStride + co) * HW + pix] = silu_act(y);
    }
}

// fusedA (round-9-proven, ~7 us): comp dw3/dw5 + comp px (1x1).
__global__ __launch_bounds__(256) void fusedA_kernel(
        const float* __restrict__ x1c,
        const float* __restrict__ w3, const float* __restrict__ s3, const float* __restrict__ b3,
        const float* __restrict__ w5, const float* __restrict__ s5, const float* __restrict__ b5,
        const float* __restrict__ pxw, const float* __restrict__ pxs, const float* __restrict__ pxb,
        float* __restrict__ y) {
    const int H = 64, Wd = 64, HW = 4096;
    int Y = blockIdx.x, og = blockIdx.y, b = blockIdx.z;
    __shared__ float cat[64][64];
    int t = threadIdx.x;
    int l = t & 63;
    int w = __builtin_amdgcn_readfirstlane(t >> 6);
    const float* src = x1c + (size_t)b * 32 * HW;
#pragma unroll
    for (int k = 0; k < 8; ++k) {
        int c = w + 4 * k;
        const float* ip = src + (size_t)c * HW;
        float acc = 0.f, sc, bi;
        if (c < 16) {
            const float* wk = w3 + c * 9;
#pragma unroll
            for (int p = 0; p < 3; ++p) {
                int iy = Y + p - 1;
                if ((unsigned)iy >= (unsigned)H) continue;
#pragma unroll
                for (int kx = 0; kx < 3; ++kx) {
                    int ix = l + kx - 1;
                    if ((unsigned)ix >= (unsigned)Wd) continue;
                    acc = fmaf(ip[iy * Wd + ix], wk[p * 3 + kx], acc);
                }
            }
            sc = s3[c]; bi = b3[c];
        } else {
            const float* wk = w5 + (c - 16) * 25;
#pragma unroll
            for (int p = 0; p < 5; ++p) {
                int iy = Y + p - 2;
                if ((unsigned)iy >= (unsigned)H) continue;
#pragma unroll
                for (int kx = 0; kx < 5; ++kx) {
                    int ix = l + kx - 2;
                    if ((unsigned)ix >= (unsigned)Wd) continue;
                    acc = fmaf(ip[iy * Wd + ix], wk[p * 5 + kx], acc);
                }
            }
            sc = s5[c - 16]; bi = b5[c - 16];
        }
        cat[c][l] = ip[Y * Wd + l];
        cat[32 + c][l] = silu_act(fmaf(acc, sc, bi));
    }
    __syncthreads();
    {
        int co0 = og * 16 + w * 4;
        const float* wp = pxw + (size_t)co0 * 64;
        float acc[4] = {0.f, 0.f, 0.f, 0.f};
#pragma unroll 8
        for (int ci = 0; ci < 64; ++ci) {
            float xv = cat[ci][l];
#pragma unroll
            for (int k = 0; k < 4; ++k)
                acc[k] = fmaf(xv, wp[k * 64 + ci], acc[k]);
        }
#pragma unroll
        for (int k = 0; k < 4; ++k) {
            int co = co0 + k;
            y[((size_t)b * 64 + co) * HW + Y * Wd + l] =
                silu_act(fmaf(acc[k], pxs[co], pxb[co]));
        }
    }
}

// fusedB-lite: enc dw3/dw5 + enc px (1x1), exact fusedA shape.
// Block = (Y, og in 0..4, b) = 640 blocks, 320 threads (5 waves).
// Wave w: dw channels c = w + 5k (k<10, unguarded); px outputs
// co = og*20 + w*4 + {0..3} with wave-uniform (SGPR) weights. Raw wraw out.
__global__ __launch_bounds__(320) void fusedB_kernel(
        const float* __restrict__ x1e,
        const float* __restrict__ w3, const float* __restrict__ s3, const float* __restrict__ b3,
        const float* __restrict__ w5, const float* __restrict__ s5, const float* __restrict__ b5,
        const float* __restrict__ pxw, const float* __restrict__ pxs, const float* __restrict__ pxb,
        float* __restrict__ wraw) {
    const int H = 64, Wd = 64, HW = 4096;
    int Y = blockIdx.x, og = blockIdx.y, b = blockIdx.z;
    __shared__ float cat[100][64];    // x1e (0..49), dw (50..99)
    int t = threadIdx.x;
    int l = t & 63;
    int w = __builtin_amdgcn_readfirstlane(t >> 6);   // 0..4
    const float* src = x1e + (size_t)b * 50 * HW;
#pragma unroll
    for (int k = 0; k < 10; ++k) {
        int c = w + 5 * k;            // covers 0..49 exactly
        const float* ip = src + (size_t)c * HW;
        float acc = 0.f, sc, bi;
        if (c < 25) {
            const float* wk = w3 + c * 9;
#pragma unroll
            for (int p = 0; p < 3; ++p) {
                int iy = Y + p - 1;
                if ((unsigned)iy >= (unsigned)H) continue;
#pragma unroll
                for (int kx = 0; kx < 3; ++kx) {
                    int ix = l + kx - 1;
                    if ((unsigned)ix >= (unsigned)Wd) continue;
                    acc = fmaf(ip[iy * Wd + ix], wk[p * 3 + kx], acc);
                }
            }
            sc = s3[c]; bi = b3[c];
        } else {
            const float* wk = w5 + (c - 25) * 25;
#pragma unroll
            for (int p = 0; p < 5; ++p) {
                int iy = Y + p - 2;
                if ((unsigned)iy >= (unsigned)H) continue;
#pragma unroll
                for (int kx = 0; kx < 5; ++kx) {
                    int ix = l + kx - 2;
                    if ((unsigned)ix >= (unsigned)Wd) continue;
                    acc = fmaf(ip[iy * Wd + ix], wk[p * 5 + kx], acc);
                }
            }
            sc = s5[c - 25]; bi = b5[c - 25];
        }
        cat[c][l] = ip[Y * Wd + l];
        cat[50 + c][l] = silu_act(fmaf(acc, sc, bi));
    }
    __syncthreads();
    // enc px: wave w computes co = og*20 + w*4 + {0..3}
    {
        int co0 = og * 20 + w * 4;
        const float* wp = pxw + (size_t)co0 * 100;
        float acc[4] = {0.f, 0.f, 0.f, 0.f};
#pragma unroll 10
        for (int ci = 0; ci < 100; ++ci) {
            float xv = cat[ci][l];
#pragma unroll
            for (int k = 0; k < 4; ++k)
                acc[k] = fmaf(xv, wp[k * 100 + ci], acc[k]);
        }
#pragma unroll
        for (int k = 0; k < 4; ++k) {
            int co = co0 + k;
            wraw[((size_t)b * 100 + co) * HW + Y * Wd + l] =
                silu_act(fmaf(acc[k], pxs[co], pxb[co]));
        }
    }
}

// CARAFE v6 (round-11-proven, VERBATIM): spill-free, 25 weight regs.
// Thread = (l = t&63, rp = t>>6); 8 channels x 1 output pixel.
// Block = (Y, 8-ch chunk, b) -> 2048 blocks, LDS 10.9 KB.
__global__ __launch_bounds__(256) void carafe_kernel(
        const float* __restrict__ X, const float* __restrict__ wraw,
        float* __restrict__ out) {
    const int H = 64, Wd = 64, C = 128, Ho = 128, Wo = 128, HW = H * Wd;
    int Y = blockIdx.x;           // 0..63
    int cchunk = blockIdx.y;      // 0..15 (8 channels each)
    int b = blockIdx.z;
    __shared__ float xs[8][5][68];    // zero-padded cols: col = ix+2
    int t = threadIdx.x;
    int c0 = cchunk * 8;
    const float* Xb = X + ((size_t)b * C + c0) * HW;
    for (int i = t; i < 8 * 5 * 68; i += 256) {
        int col = i % 68;
        int tmp = i / 68;
        int p = tmp % 5;
        int c = tmp / 5;
        int iy = Y + p - 2, ix = col - 2;
        float v = 0.f;
        if ((unsigned)iy < (unsigned)H && (unsigned)ix < (unsigned)Wd)
            v = Xb[(size_t)c * HW + iy * Wd + ix];
        xs[c][p][col] = v;
    }
    int l = t & 63;               // ox-pair: Xc = l
    int rp = t >> 6;              // 0..3: oy-offset = rp>>1, ox-parity = rp&1
    // load this thread's 25 raw weights (coalesced over l): chW = j*4 + rp
    const float* wb = wraw + (size_t)b * 100 * HW + Y * Wd + l;
    float wreg[25];
#pragma unroll
    for (int j = 0; j < 25; ++j)
        wreg[j] = wb[(size_t)(j * 4 + rp) * HW];
    // in-register softmax over the 25 taps
    {
        float m = -1e30f;
#pragma unroll
        for (int j = 0; j < 25; ++j) m = fmaxf(m, wreg[j]);
        float s = 0.f;
#pragma unroll
        for (int j = 0; j < 25; ++j) { wreg[j] = __expf(wreg[j] - m); s += wreg[j]; }
        float inv = 1.f / s;
#pragma unroll
        for (int j = 0; j < 25; ++j) wreg[j] *= inv;
    }
    __syncthreads();

    int oy = 2 * Y + (rp >> 1);
    int ox = 2 * l + (rp & 1);
#pragma unroll
    for (int k = 0; k < 8; ++k) {
        float acc = 0.f;
#pragma unroll
        for (int p = 0; p < 5; ++p)
#pragma unroll
            for (int q = 0; q < 5; ++q)
                acc = fmaf(wreg[p * 5 + q], xs[k][p][l + q], acc);
        out[(((size_t)b * C + (c0 + k)) * Ho + oy) * Wo + ox] = acc;
    }
}

extern "C" void kernel_launch(void* const* d_in, const int* in_sizes, int n_in,
                              void* d_out, int out_size, void* d_ws, size_t ws_size,
                              hipStream_t stream) {
    const float* X          = (const float*)d_in[0];
    const float* comp_cv1_w = (const float*)d_in[1];
    const float* comp_cv1_s = (const float*)d_in[2];
    const float* comp_cv1_b = (const float*)d_in[3];
    const float* comp_dw3_w = (const float*)d_in[4];
    const float* comp_dw3_s = (const float*)d_in[5];
    const float* comp_dw3_b = (const float*)d_in[6];
    const float* comp_dw5_w = (const float*)d_in[7];
    const float* comp_dw5_s = (const float*)d_in[8];
    const float* comp_dw5_b = (const float*)d_in[9];
    const float* comp_px_w  = (const float*)d_in[10];
    const float* comp_px_s  = (const float*)d_in[11];
    const float* comp_px_b  = (const float*)d_in[12];
    const float* enc_cv1_w  = (const float*)d_in[13];
    const float* enc_cv1_s  = (const float*)d_in[14];
    const float* enc_cv1_b  = (const float*)d_in[15];
    const float* enc_dw3_w  = (const float*)d_in[16];
    const float* enc_dw3_s  = (const float*)d_in[17];
    const float* enc_dw3_b  = (const float*)d_in[18];
    const float* enc_dw5_w  = (const float*)d_in[19];
    const float* enc_dw5_s  = (const float*)d_in[20];
    const float* enc_dw5_b  = (const float*)d_in[21];
    const float* enc_px_w   = (const float*)d_in[22];
    const float* enc_px_s   = (const float*)d_in[23];
    const float* enc_px_b   = (const float*)d_in[24];
    float* out = (float*)d_out;

    const int B = 2, HW = 64 * 64;
    float* x1c  = (float*)d_ws;                  // [B, 32, HW]
    float* yc   = x1c  + (size_t)B * 32 * HW;    // [B, 64, HW]
    float* x1e  = yc   + (size_t)B * 64 * HW;    // [B, 50, HW]
    float* wraw = x1e  + (size_t)B * 50 * HW;    // [B, 100, HW]

    int pixBlocks = (B * HW + 255) / 256;   // 32

    // 1. comp cv1 (1x1, 128 -> 32)
    pw_conv_silu<4, 128><<<dim3(pixBlocks, 8), 256, 0, stream>>>(
        X, HW, B, comp_cv1_w, comp_cv1_s, comp_cv1_b, x1c, 32);

    // 2. comp dw + comp px (fusedA, 512 blocks)
    fusedA_kernel<<<dim3(64, 4, B), 256, 0, stream>>>(
        x1c,
        comp_dw3_w, comp_dw3_s, comp_dw3_b,
        comp_dw5_w, comp_dw5_s, comp_dw5_b,
        comp_px_w, comp_px_s, comp_px_b,
        yc);

    // 3. enc cv1 (1x1, 64 -> 50)
    pw_conv_silu<5, 64><<<dim3(pixBlocks, 10), 256, 0, stream>>>(
        yc, HW, B, enc_cv1_w, enc_cv1_s, enc_cv1_b, x1e, 50);

    // 4. enc dw + enc px (fusedB-lite, 640 blocks x 320 thr) -- THE one change
    fusedB_kernel<<<dim3(64, 5, B), 320, 0, stream>>>(
        x1e,
        enc_dw3_w, enc_dw3_s, enc_dw3_b,
        enc_dw5_w, enc_dw5_s, enc_dw5_b,
        enc_px_w, enc_px_s, enc_px_b,
        wraw);

    // 5. CARAFE v6 (round-11 verbatim), 2048 blocks
    carafe_kernel<<<dim3(64, 16, B), 256, 0, stream>>>(X, wraw, out);
}